// Round 3
// baseline (214.159 us; speedup 1.0000x reference)
//
#include <hip/hip_runtime.h>

// FEM stiffness matvec KU = sum_e scatter(K_type(e) @ gather(U, e)).
//
// Round 17 = R16 (212.0 us; K1 71.5 us) + block-LOCAL type sort in K1.
// R15 lesson: global type-sort gave uniform filter reads but 2.8x DRAM
// (random nodIdx gathers + fragmented record runs). R17 keeps each block on
// its own SEQUENTIAL 2048-element chunk (DRAM pattern identical) and sorts
// only the processing order inside the block: 64-bin LDS counting sort
// (count -> wave-0 shfl scan -> atomic placement, 4 KB sOrder + 2 KB sType).
// nodIdx is then gathered within the block's 64 KB window (lines fully
// consumed -> FETCH unchanged); filter ds_read_b128 become 2-3-way
// broadcasts instead of 64-way scatters.
// K1 counter arithmetic (R16): 1.125M ds_read_b128 wave-instrs x ~12 cyc
// + 29.5K conflict cyc/CU = ~82K of 171K cycles/CU (~48%) -- LDS is the
// bottleneck pipe (VALU 19%, HBM 36%). Broadcast uniformity is the only
// fix; padding can't help (64 distinct addresses = 8 cyc floor).
// Carries: K2_TPB 1024 (R16: +3.5 us), fp32 LDS filters stride 580,
// EPT=2 early gather issue, bf16-packed U, 8 B bf16 records,
// block-aggregated tail reservation, launch_bounds (1024,4).
// R13 lesson: ~110 us of the total is harness/graph overhead, not kernels.

#define NTYPES    64
#define KSTRIDE   580            // fp32 words per type: 2320 B, 16 B-aligned
#define RSHIFT    11
#define RNODES    2048
#define MAXB      512
#define CAP       10240          // mean 8180/bucket, huge slack (even: 16 B pairs)
#define K1_TPB    1024
#define K1_EPT    2
#define K1_CHUNK  (K1_TPB * K1_EPT)
#define K2_TPB    1024
#define PREP_TPB  256

typedef int          nint4  __attribute__((ext_vector_type(4)));
typedef unsigned int nuint2 __attribute__((ext_vector_type(2)));
typedef unsigned int nuint4 __attribute__((ext_vector_type(4)));

__device__ __forceinline__ unsigned bf16_rne(float f) {
    unsigned b = __float_as_uint(f);
    return (b + 0x7FFFu + ((b >> 16) & 1u)) >> 16;
}

// ---- phase 0: pack U -> bf16 triples; zero KU and tails -------------------

__global__ __launch_bounds__(PREP_TPB) void pack_u_kernel(
    const float* __restrict__ U, nuint2* __restrict__ Ub,
    float* __restrict__ KU, unsigned* __restrict__ tails,
    int n_nodes, int n_buckets)
{
    int n = blockIdx.x * PREP_TPB + threadIdx.x;
    if (n < n_buckets) tails[n] = 0;
    if (n >= n_nodes) return;
    const float* up = U + (size_t)n * 3;
    unsigned bx = bf16_rne(up[0]);
    unsigned by = bf16_rne(up[1]);
    unsigned bz = bf16_rne(up[2]);
    nuint2 v = { bx | (by << 16), bz };
    Ub[n] = v;
    KU[3 * n + 0] = 0.f;
    KU[3 * n + 1] = 0.f;
    KU[3 * n + 2] = 0.f;
}

// ---- phase 1: compute + bin (block-local type sort) ----------------------

__global__ __launch_bounds__(K1_TPB, 4) void feconv_bin_kernel(
    const nuint2* __restrict__ Ub,      // [N] packed bf16 x,y,z
    const float* __restrict__ K,        // [64, 24, 24]
    const int*   __restrict__ types,    // [E]
    const int*   __restrict__ nodIdx,   // [E, 8]
    float*       __restrict__ KU,       // overflow fallback only
    unsigned*    __restrict__ tails,    // [n_buckets]
    nuint2*      __restrict__ recs,     // [n_buckets * CAP]
    int n_elems, int n_buckets)
{
    extern __shared__ float sK[];       // [64 * KSTRIDE] words, per-type rows
    __shared__ unsigned       sCnt[MAXB];
    __shared__ unsigned       sBase[MAXB];
    __shared__ unsigned       sTCnt[NTYPES];   // type counts / cursors
    __shared__ unsigned       sTOff[NTYPES];   // exclusive type offsets
    __shared__ unsigned short sOrder[K1_CHUNK];// sorted order -> local elem idx
    __shared__ unsigned char  sType[K1_CHUNK]; // local elem idx -> type

    for (int w = threadIdx.x; w < NTYPES * 576; w += K1_TPB) {
        int t = w / 576;
        int r = w - t * 576;
        sK[t * KSTRIDE + r] = K[w];
    }
    for (int i = threadIdx.x; i < n_buckets; i += K1_TPB) sCnt[i] = 0;
    if (threadIdx.x < NTYPES) sTCnt[threadIdx.x] = 0;
    __syncthreads();

    const int base = blockIdx.x * K1_CHUNK;
    int cnt_chunk = n_elems - base;
    if (cnt_chunk > K1_CHUNK) cnt_chunk = K1_CHUNK;

    // S0: coalesced type load + per-type count
    int myT[K1_EPT];
#pragma unroll
    for (int k = 0; k < K1_EPT; ++k) {
        int li = threadIdx.x + k * K1_TPB;
        myT[k] = -1;
        if (li < cnt_chunk) {
            int t = __builtin_nontemporal_load(&types[base + li]);
            myT[k] = t;
            sType[li] = (unsigned char)t;
            atomicAdd(&sTCnt[t], 1u);
        }
    }
    __syncthreads();

    // S1: exclusive prefix scan over 64 type counts (wave 0 shfl scan)
    if (threadIdx.x < NTYPES) {
        unsigned v = sTCnt[threadIdx.x];
        unsigned s = v;
#pragma unroll
        for (int d = 1; d < NTYPES; d <<= 1) {
            unsigned o = __shfl_up(s, d, 64);
            if ((int)threadIdx.x >= d) s += o;
        }
        sTOff[threadIdx.x] = s - v;
        sTCnt[threadIdx.x] = 0;          // reuse as placement cursor
    }
    __syncthreads();

    // S2: scatter local indices into type-sorted order
#pragma unroll
    for (int k = 0; k < K1_EPT; ++k) {
        int li = threadIdx.x + k * K1_TPB;
        if (myT[k] >= 0) {
            unsigned p = sTOff[myT[k]] + atomicAdd(&sTCnt[myT[k]], 1u);
            sOrder[p] = (unsigned short)li;
        }
    }
    __syncthreads();

    int     nodes[K1_EPT][8];
    int     tt[K1_EPT];
    nuint2  uu[K1_EPT][8];              // in-flight packed gathers

    // pass A: (type-sorted) connectivity + EARLY gather issue + bucket count
    // nodIdx reads stay within this block's 64 KB window: every line fetched
    // is fully consumed by the block -> DRAM traffic unchanged vs sequential.
#pragma unroll
    for (int k = 0; k < K1_EPT; ++k) {
        int slot = threadIdx.x + k * K1_TPB;
        tt[k] = -1;
        if (slot < cnt_chunk) {
            int li = sOrder[slot];
            int e  = base + li;
            tt[k] = sType[li];
            const nint4* q = (const nint4*)(nodIdx + (size_t)e * 8);
            nint4 a = q[0];
            nint4 b = q[1];
            nodes[k][0] = a.x; nodes[k][1] = a.y; nodes[k][2] = a.z; nodes[k][3] = a.w;
            nodes[k][4] = b.x; nodes[k][5] = b.y; nodes[k][6] = b.z; nodes[k][7] = b.w;
#pragma unroll
            for (int j = 0; j < 8; ++j)
                uu[k][j] = Ub[nodes[k][j]];          // issue all 16 gathers now
#pragma unroll
            for (int j = 0; j < 8; ++j)
                atomicAdd(&sCnt[(unsigned)nodes[k][j] >> RSHIFT], 1u);
        }
    }
    __syncthreads();

    // pass B: one global tail reservation per (block, bucket)
    for (int b = threadIdx.x; b < n_buckets; b += K1_TPB) {
        unsigned c = sCnt[b];
        sBase[b] = c ? atomicAdd(&tails[b], c) : 0u;
        sCnt[b] = 0;                     // reuse as local cursor
    }
    __syncthreads();

    // pass C: unpack, matvec; filter reads now ~wave-uniform -> LDS broadcast
#pragma unroll
    for (int k = 0; k < K1_EPT; ++k) {
        if (tt[k] < 0) continue;

        float ue[24];
#pragma unroll
        for (int j = 0; j < 8; ++j) {
            nuint2 v = uu[k][j];
            ue[3 * j + 0] = __uint_as_float(v.x << 16);
            ue[3 * j + 1] = __uint_as_float(v.x & 0xFFFF0000u);
            ue[3 * j + 2] = __uint_as_float(v.y << 16);
        }

        const float4* Kt4 = (const float4*)(sK + tt[k] * KSTRIDE);
#pragma unroll
        for (int j = 0; j < 8; ++j) {
            float a0 = 0.f, a1 = 0.f, a2 = 0.f;
#pragma unroll
            for (int q = 0; q < 6; ++q) {
                float4 k0 = Kt4[(3 * j + 0) * 6 + q];
                float4 k1 = Kt4[(3 * j + 1) * 6 + q];
                float4 k2 = Kt4[(3 * j + 2) * 6 + q];
                float u0 = ue[4 * q + 0], u1 = ue[4 * q + 1];
                float u2 = ue[4 * q + 2], u3 = ue[4 * q + 3];
                a0 += k0.x * u0 + k0.y * u1 + k0.z * u2 + k0.w * u3;
                a1 += k1.x * u0 + k1.y * u1 + k1.z * u2 + k1.w * u3;
                a2 += k2.x * u0 + k2.y * u1 + k2.z * u2 + k2.w * u3;
            }
            unsigned n = (unsigned)nodes[k][j];
            unsigned b = n >> RSHIFT;
            unsigned pos = sBase[b] + atomicAdd(&sCnt[b], 1u);
            if (pos < CAP) {
                unsigned local = n & (RNODES - 1);
                nuint2 r = { bf16_rne(a0) | (bf16_rne(a1) << 16),
                             bf16_rne(a2) | (local << 16) };
                recs[(size_t)b * CAP + pos] = r;
            } else {  // statistically unreachable; absolute correctness
                atomicAdd(&KU[(size_t)n * 3 + 0], a0);
                atomicAdd(&KU[(size_t)n * 3 + 1], a1);
                atomicAdd(&KU[(size_t)n * 3 + 2], a2);
            }
        }
    }
}

// ---- phase 2: accumulate per bucket --------------------------------------

__global__ __launch_bounds__(K2_TPB) void feconv_acc_kernel(
    const nuint2*   __restrict__ recs,
    const unsigned* __restrict__ tails,
    float*          __restrict__ KU,     // [N, 3], pre-zeroed
    int n_nodes)
{
    __shared__ float sAcc[RNODES * 3];   // 24 KB; TPB 1024 -> 2 blocks/CU
    const int b = blockIdx.x;

    for (int i = threadIdx.x; i < RNODES * 3; i += K2_TPB) sAcc[i] = 0.f;
    __syncthreads();

    unsigned cnt = tails[b];
    if (cnt > CAP) cnt = CAP;
    const nuint2* base = recs + (size_t)b * CAP;
    const nuint4* base4 = (const nuint4*)base;       // 16 B-aligned (CAP even)

    unsigned npairs = cnt >> 1;
    for (unsigned i = threadIdx.x; i < npairs; i += K2_TPB) {
        nuint4 p = base4[i];                          // two records, one load
        unsigned o0 = (p.y >> 16) * 3;
        atomicAdd(&sAcc[o0 + 0], __uint_as_float(p.x << 16));
        atomicAdd(&sAcc[o0 + 1], __uint_as_float(p.x & 0xFFFF0000u));
        atomicAdd(&sAcc[o0 + 2], __uint_as_float(p.y << 16));
        unsigned o1 = (p.w >> 16) * 3;
        atomicAdd(&sAcc[o1 + 0], __uint_as_float(p.z << 16));
        atomicAdd(&sAcc[o1 + 1], __uint_as_float(p.z & 0xFFFF0000u));
        atomicAdd(&sAcc[o1 + 2], __uint_as_float(p.w << 16));
    }
    if ((cnt & 1u) && threadIdx.x == 0) {             // odd tail record
        nuint2 r = base[cnt - 1];
        unsigned o = (r.y >> 16) * 3;
        atomicAdd(&sAcc[o + 0], __uint_as_float(r.x << 16));
        atomicAdd(&sAcc[o + 1], __uint_as_float(r.x & 0xFFFF0000u));
        atomicAdd(&sAcc[o + 2], __uint_as_float(r.y << 16));
    }
    __syncthreads();

    const int nbase = b * RNODES;
    int limit = n_nodes - nbase;
    if (limit > RNODES) limit = RNODES;
    limit *= 3;
    float* out = KU + (size_t)nbase * 3;
    for (int i = threadIdx.x; i < limit; i += K2_TPB) out[i] += sAcc[i];
}

// ---- fallback (round-0 style) --------------------------------------------

__global__ __launch_bounds__(256) void feconv_elem_kernel(
    const float* __restrict__ U, const float* __restrict__ K,
    const int* __restrict__ types, const int* __restrict__ nodIdx,
    float* __restrict__ KU, int n_elems)
{
    int e = blockIdx.x * blockDim.x + threadIdx.x;
    if (e >= n_elems) return;
    int t = types[e];
    const int4* idx4 = (const int4*)(nodIdx + (size_t)e * 8);
    int4 iA = idx4[0], iB = idx4[1];
    int nodes[8] = {iA.x, iA.y, iA.z, iA.w, iB.x, iB.y, iB.z, iB.w};
    float ue[24];
#pragma unroll
    for (int j = 0; j < 8; ++j) {
        const float* up = U + (size_t)nodes[j] * 3;
        ue[3 * j + 0] = up[0]; ue[3 * j + 1] = up[1]; ue[3 * j + 2] = up[2];
    }
    const float* Kt = K + (size_t)t * 576;
#pragma unroll
    for (int i = 0; i < 24; ++i) {
        const float4* row = (const float4*)(Kt + i * 24);
        float acc = 0.f;
#pragma unroll
        for (int q = 0; q < 6; ++q) {
            float4 k = row[q];
            acc += k.x * ue[4 * q + 0] + k.y * ue[4 * q + 1]
                 + k.z * ue[4 * q + 2] + k.w * ue[4 * q + 3];
        }
        atomicAdd(&KU[(size_t)nodes[i / 3] * 3 + (i % 3)], acc);
    }
}

extern "C" void kernel_launch(void* const* d_in, const int* in_sizes, int n_in,
                              void* d_out, int out_size, void* d_ws, size_t ws_size,
                              hipStream_t stream) {
    const float* U      = (const float*)d_in[0];
    const float* Kf     = (const float*)d_in[1];
    const int*   types  = (const int*)d_in[2];
    const int*   nodIdx = (const int*)d_in[3];
    float*       KU     = (float*)d_out;

    const int n_elems = in_sizes[2];
    const int n_nodes = in_sizes[0] / 3;
    const int n_buckets = (n_nodes + RNODES - 1) / RNODES;   // 489 for N=1M

    // ws layout: [0, 4096) tails | [4096, +8B*n_nodes) Ub | then recs
    const size_t ub_off  = 4096;
    const size_t rec_off = ub_off + (((size_t)n_nodes * 8 + 255) & ~255ull);
    const size_t need    = rec_off + (size_t)n_buckets * CAP * 8;

    if (n_buckets <= MAXB && ws_size >= need) {
        unsigned* tails = (unsigned*)d_ws;
        nuint2*   Ub    = (nuint2*)((char*)d_ws + ub_off);
        nuint2*   recs  = (nuint2*)((char*)d_ws + rec_off);

        int gridP = (n_nodes + PREP_TPB - 1) / PREP_TPB;
        pack_u_kernel<<<gridP, PREP_TPB, 0, stream>>>(
            U, Ub, KU, tails, n_nodes, n_buckets);

        size_t lds_bytes = (size_t)NTYPES * KSTRIDE * sizeof(float);  // 148,480
        int grid1 = (n_elems + K1_CHUNK - 1) / K1_CHUNK;               // 245
        feconv_bin_kernel<<<grid1, K1_TPB, lds_bytes, stream>>>(
            Ub, Kf, types, nodIdx, KU, tails, recs, n_elems, n_buckets);
        feconv_acc_kernel<<<n_buckets, K2_TPB, 0, stream>>>(
            recs, tails, KU, n_nodes);
    } else {
        (void)hipMemsetAsync(KU, 0, (size_t)out_size * sizeof(float), stream);
        int block = 256;
        int grid = (n_elems + block - 1) / block;
        feconv_elem_kernel<<<grid, block, 0, stream>>>(
            U, Kf, types, nodIdx, KU, n_elems);
    }
}